// Round 15
// baseline (82.063 us; speedup 1.0000x reference)
//
#include <hip/hip_runtime.h>

// Capped simplex projection: per row, w = clip(z - tau, 0, u), sum(w) = 1.
// One wave (64 lanes) per row; 64 fp32 elements per lane in registers.
//
// R14 = R13 with the per-wave serial critical path shortened:
//  - BB_ITERS 10 -> 4: the 3 multisection rounds (18 bits) absorb the wider
//    bracket (~0.02*rt); tap window grows to ~0.02rt+0.04 => E[taps] 5-10,
//    still << NTAPS=24. Saves ~540cy of serial DPP-reduce chain per wave.
//  - Two-ended band compaction: two independent 32-element half-scans, half A
//    filling slots[0..] up, half B filling slots[5-..] down (slot order is
//    irrelevant; overflow A+B>=7 detected -> fallback; indices clamped).
//    Halves the loop-carried bcnt chain latency.
//  - Everything else identical to R13 (rt-derived band, pure load loop,
//    MS + tap epilogue, NT writes, always-correct fallback).

#define N_ASSETS 4096
#define N_SAMPLES 16384
#define MAX_W 0.02f
#define EPS 1e-7f
#define KRANK 50             // ceil(1 / MAX_W)
#define FB_ITERS 17          // fallback sum-scan iterations
#define MS_ROUNDS 3          // multisection rounds (6 bits each)
#define NTAPS 24
#define BB_ITERS 4           // band-local bisect iterations
#define T1MULT 2.09f
#define T2MULT 2.41f

typedef __attribute__((ext_vector_type(2))) float f32x2;
typedef __attribute__((ext_vector_type(4))) float f32x4;

#define PKADD(d, a, b) asm("v_pk_add_f32 %0, %1, %2" : "=v"(d) : "v"(a), "v"(b))
#define PKMUL(d, a, b) asm("v_pk_mul_f32 %0, %1, %2" : "=v"(d) : "v"(a), "v"(b))

__device__ __forceinline__ float clipu(float v) {
    return __builtin_amdgcn_fmed3f(v, 0.0f, MAX_W);
}
__device__ __forceinline__ float bc_int_as_f(int v) {
    union { int i; float f; } u; u.i = v; return u.f;
}
__device__ __forceinline__ int bc_f_as_int(float v) {
    union { int i; float f; } u; u.f = v; return u.i;
}

template <int CTRL, int RMASK, bool BC>
__device__ __forceinline__ float dpp_add_step(float x) {
    int t = __builtin_amdgcn_update_dpp(0, bc_f_as_int(x), CTRL, RMASK, 0xF, BC);
    return x + bc_int_as_f(t);
}
__device__ __forceinline__ float wave_sum(float v) {
    v = dpp_add_step<0x111, 0xF, true>(v);
    v = dpp_add_step<0x112, 0xF, true>(v);
    v = dpp_add_step<0x114, 0xF, true>(v);
    v = dpp_add_step<0x118, 0xF, true>(v);
    v = dpp_add_step<0x142, 0xA, false>(v);
    v = dpp_add_step<0x143, 0xC, false>(v);
    return bc_int_as_f(__builtin_amdgcn_readlane(bc_f_as_int(v), 63));
}
template <int CTRL, int RMASK, bool BC>
__device__ __forceinline__ int dpp_iadd_step(int x) {
    int t = __builtin_amdgcn_update_dpp(0, x, CTRL, RMASK, 0xF, BC);
    return x + t;
}
__device__ __forceinline__ int wave_isum(int v) {
    v = dpp_iadd_step<0x111, 0xF, true>(v);
    v = dpp_iadd_step<0x112, 0xF, true>(v);
    v = dpp_iadd_step<0x114, 0xF, true>(v);
    v = dpp_iadd_step<0x118, 0xF, true>(v);
    v = dpp_iadd_step<0x142, 0xA, false>(v);
    v = dpp_iadd_step<0x143, 0xC, false>(v);
    return __builtin_amdgcn_readlane(v, 63);
}
template <int CTRL, int RMASK>
__device__ __forceinline__ float dpp_min_step(float x) {
    int xi = bc_f_as_int(x);
    int t = __builtin_amdgcn_update_dpp(xi, xi, CTRL, RMASK, 0xF, false);
    return fminf(x, bc_int_as_f(t));
}
template <int CTRL, int RMASK>
__device__ __forceinline__ float dpp_max_step(float x) {
    int xi = bc_f_as_int(x);
    int t = __builtin_amdgcn_update_dpp(xi, xi, CTRL, RMASK, 0xF, false);
    return fmaxf(x, bc_int_as_f(t));
}
__device__ __forceinline__ float wave_min(float v) {
    v = dpp_min_step<0x111, 0xF>(v); v = dpp_min_step<0x112, 0xF>(v);
    v = dpp_min_step<0x114, 0xF>(v); v = dpp_min_step<0x118, 0xF>(v);
    v = dpp_min_step<0x142, 0xA>(v); v = dpp_min_step<0x143, 0xC>(v);
    return bc_int_as_f(__builtin_amdgcn_readlane(bc_f_as_int(v), 63));
}
__device__ __forceinline__ float wave_max(float v) {
    v = dpp_max_step<0x111, 0xF>(v); v = dpp_max_step<0x112, 0xF>(v);
    v = dpp_max_step<0x114, 0xF>(v); v = dpp_max_step<0x118, 0xF>(v);
    v = dpp_max_step<0x142, 0xA>(v); v = dpp_max_step<0x143, 0xC>(v);
    return bc_int_as_f(__builtin_amdgcn_readlane(bc_f_as_int(v), 63));
}

// Full packed scan: sum of clip(z - mid) over 32 pairs (fallback path only).
__device__ __forceinline__ float scan_sum(const f32x2* zp, float mid) {
    f32x2 nm; nm.x = -mid; nm.y = -mid;
    f32x2 acc0 = {0.f, 0.f}, acc1 = {0.f, 0.f}, acc2 = {0.f, 0.f}, acc3 = {0.f, 0.f};
    #pragma unroll
    for (int k = 0; k < 32; k += 4) {
        f32x2 t0, t1, t2, t3;
        PKADD(t0, zp[k+0], nm);
        PKADD(t1, zp[k+1], nm);
        PKADD(t2, zp[k+2], nm);
        PKADD(t3, zp[k+3], nm);
        t0.x = clipu(t0.x); t0.y = clipu(t0.y);
        t1.x = clipu(t1.x); t1.y = clipu(t1.y);
        t2.x = clipu(t2.x); t2.y = clipu(t2.y);
        t3.x = clipu(t3.x); t3.y = clipu(t3.y);
        PKADD(acc0, acc0, t0);
        PKADD(acc1, acc1, t1);
        PKADD(acc2, acc2, t2);
        PKADD(acc3, acc3, t3);
    }
    PKADD(acc0, acc0, acc1);
    PKADD(acc2, acc2, acc3);
    PKADD(acc0, acc0, acc2);
    return acc0.x + acc0.y;
}

__global__ __launch_bounds__(256) void sparsemax_alloc_kernel(
    const float* __restrict__ x,
    const float* __restrict__ temperature,
    float* __restrict__ out) {

    __shared__ float band_lds[4][64][6];
    __shared__ float amb_lds[4][NTAPS];

    const int wave = threadIdx.x >> 6;          // 4 waves per block
    const int lane = threadIdx.x & 63;
    const int row  = blockIdx.x * 4 + wave;

    const float4* xr   = reinterpret_cast<const float4*>(x + (size_t)row * N_ASSETS);
    f32x4*        outr = reinterpret_cast<f32x4*>(out + (size_t)row * N_ASSETS);

    const float rt = 1.0f / temperature[row];   // sigma_z (x ~ N(0,1) rows)
    f32x2 rt2; rt2.x = rt; rt2.y = rt;

    const float t1 = T1MULT * rt;
    const float t2 = T2MULT * rt;
    const float bandLo = t1 - MAX_W;
    const float bandHi = t2 + MAX_W;

    // ---- Pure load loop: load + scale only (pipelineable) ----
    f32x2 zp[32];
    #pragma unroll
    for (int k = 0; k < 16; ++k) {
        float4 v = xr[k * 64 + lane];
        f32x2 lohalf, hihalf;
        lohalf.x = v.x; lohalf.y = v.y;
        hihalf.x = v.z; hihalf.y = v.w;
        PKMUL(zp[2*k],   lohalf, rt2);
        PKMUL(zp[2*k+1], hihalf, rt2);
    }

    // ---- Probe/compaction scan: two independent half-scans (short chains) ----
    float* slots = &band_lds[wave][lane][0];
    #pragma unroll
    for (int i = 0; i < 6; ++i) slots[i] = bandLo;   // sentinel

    int cBH_a = 0, bcnt_a = 0;     // half A: zp[0..15], fills slots[0..] up
    int cBH_b = 0, bcnt_b = 0;     // half B: zp[16..31], fills slots[5-..] down
    #pragma unroll
    for (int k = 0; k < 16; ++k) {
        #pragma unroll
        for (int c = 0; c < 2; ++c) {
            const float va = (c == 0) ? zp[k].x : zp[k].y;
            const bool hiA = va > bandHi;
            cBH_a += hiA ? 1 : 0;
            const bool inA = (va > bandLo) && !hiA;
            if (inA) {
                slots[bcnt_a < 6 ? bcnt_a : 5] = va;
                ++bcnt_a;
            }
            const float vb = (c == 0) ? zp[16 + k].x : zp[16 + k].y;
            const bool hiB = vb > bandHi;
            cBH_b += hiB ? 1 : 0;
            const bool inB = (vb > bandLo) && !hiB;
            if (inB) {
                slots[bcnt_b < 6 ? 5 - bcnt_b : 0] = vb;
                ++bcnt_b;
            }
        }
    }
    const int cBH = cBH_a + cBH_b;
    const int bcnt = bcnt_a + bcnt_b;
    asm volatile("s_waitcnt lgkmcnt(0)" ::: "memory");
    const float e0 = slots[0], e1 = slots[1], e2 = slots[2];
    const float e3 = slots[3], e4 = slots[4], e5 = slots[5];

    // Packed reduce: cBH (13b) | #{band>t1} (10b) | #{band>t2} (9b).
    int cg1 = (e0 > t1) + (e1 > t1) + (e2 > t1) + (e3 > t1) + (e4 > t1) + (e5 > t1);
    int cg2 = (e0 > t2) + (e1 > t2) + (e2 > t2) + (e3 > t2) + (e4 > t2) + (e5 > t2);
    const unsigned sred = (unsigned)wave_isum(cBH | (cg1 << 13) | (cg2 << 23));
    const int cBHt = (int)(sred & 0x1FFFu);
    const int c1   = cBHt + (int)((sred >> 13) & 0x3FFu);
    const int c2   = cBHt + (int)(sred >> 23);

    const bool ovf = __ballot(bcnt >= 7) != 0ULL;
    bool fastpath = (c1 >= KRANK) && (c2 < KRANK) && !ovf;

    float fbLo = 0.0f, fbHi = 0.0f;
    bool have_fb = false;
    float tau = 0.0f, tau0 = 0.0f;
    int nf_total = 0;
    const float ucut = MAX_W - EPS;

    if (fastpath) {
        // ---- Band-local count bisection (4 iters; MS absorbs the rest) ----
        float clo = t1, chi = t2;
        int c_chi = c2;
        #pragma unroll
        for (int it = 0; it < BB_ITERS; ++it) {
            const float mid = 0.5f * (clo + chi);
            int pc = (e0 > mid) + (e1 > mid) + (e2 > mid)
                   + (e3 > mid) + (e4 > mid) + (e5 > mid);
            const int cc = cBHt + wave_isum(pc);
            const bool big = (cc >= KRANK);
            clo = big ? mid : clo;
            chi = big ? chi : mid;
            c_chi = big ? c_chi : cc;
        }
        const float Lo = clo - MAX_W;
        const float Hi = chi;
        const float capTh = Hi + MAX_W;

        // ---- Taps from band regs: elements in (Lo, capTh) ----
        float za = Lo, zb = Lo, zc = Lo;
        int tcnt = 0;
        {
            const float ee[6] = {e0, e1, e2, e3, e4, e5};
            #pragma unroll
            for (int i = 0; i < 6; ++i) {
                const bool tap = (ee[i] > Lo) && (ee[i] < capTh);
                za = (tap && tcnt == 0) ? ee[i] : za;
                zb = (tap && tcnt == 1) ? ee[i] : zb;
                zc = (tap && tcnt == 2) ? ee[i] : zc;
                tcnt += tap ? 1 : 0;
            }
        }
        const unsigned long long b1 = __ballot(tcnt >= 1);
        const unsigned long long b2 = __ballot(tcnt >= 2);
        const unsigned long long b3 = __ballot(tcnt >= 3);
        const unsigned long long b4 = __ballot(tcnt >= 4);
        int off = __builtin_amdgcn_mbcnt_hi((unsigned)(b1 >> 32),
                  __builtin_amdgcn_mbcnt_lo((unsigned)b1, 0));
        off    += __builtin_amdgcn_mbcnt_hi((unsigned)(b2 >> 32),
                  __builtin_amdgcn_mbcnt_lo((unsigned)b2, 0));
        off    += __builtin_amdgcn_mbcnt_hi((unsigned)(b3 >> 32),
                  __builtin_amdgcn_mbcnt_lo((unsigned)b3, 0));
        const int M = __popcll(b1) + __popcll(b2) + __popcll(b3);

        if (tcnt >= 1 && off     < NTAPS) amb_lds[wave][off]     = za;
        if (tcnt >= 2 && off + 1 < NTAPS) amb_lds[wave][off + 1] = zb;
        if (tcnt >= 3 && off + 2 < NTAPS) amb_lds[wave][off + 2] = zc;
        asm volatile("s_waitcnt lgkmcnt(0)" ::: "memory");

        if ((b4 != 0ULL) || (M > NTAPS)) {
            fastpath = false;            // rare: taps overflow -> tight FB bracket
            fbLo = Lo; fbHi = Hi; have_fb = true;
        } else {
            // capcnt = #{z >= capTh} = c_chi - #{band in (chi, capTh)}
            int pcc = ((e0 > chi) && (e0 < capTh)) + ((e1 > chi) && (e1 < capTh))
                    + ((e2 > chi) && (e2 < capTh)) + ((e3 > chi) && (e3 < capTh))
                    + ((e4 > chi) && (e4 < capTh)) + ((e5 > chi) && (e5 < capTh));
            const int capcnt = c_chi - wave_isum(pcc);
            const float capC = (float)capcnt * MAX_W;

            // ---- 64-way multisection over taps (closed form) ----
            f32x2 a2[NTAPS / 2];
            #pragma unroll
            for (int i = 0; i < NTAPS / 2; ++i) {
                a2[i].x = (2*i     < M) ? amb_lds[wave][2*i]     : Lo;
                a2[i].y = (2*i + 1 < M) ? amb_lds[wave][2*i + 1] : Lo;
            }
            float lo = Lo, hi = Hi;
            #pragma unroll
            for (int r = 0; r < MS_ROUNDS; ++r) {
                const float step = (hi - lo) * 0.015625f;
                const float tl = fmaf((float)(lane + 1), step, lo);
                f32x2 ntl; ntl.x = -tl; ntl.y = -tl;
                f32x2 acc0 = {0.f, 0.f}, acc1 = {0.f, 0.f};
                #pragma unroll
                for (int i = 0; i < NTAPS / 2; i += 2) {
                    f32x2 q0, q1;
                    PKADD(q0, a2[i],   ntl);
                    PKADD(q1, a2[i+1], ntl);
                    q0.x = clipu(q0.x); q0.y = clipu(q0.y);
                    q1.x = clipu(q1.x); q1.y = clipu(q1.y);
                    PKADD(acc0, acc0, q0);
                    PKADD(acc1, acc1, q1);
                }
                PKADD(acc0, acc0, acc1);
                const float s = capC + (acc0.x + acc0.y);
                const unsigned long long mask = __ballot(s > 1.0f);
                int j = __popcll(mask);
                j = (j > 63) ? 63 : j;
                const float lo_old = lo;
                lo = fmaf((float)j, step, lo_old);
                hi = fmaf((float)(j + 1), step, lo_old);
            }
            tau0 = 0.5f * (lo + hi);

            // ---- Epilogue over taps (wave-uniform) ----
            int nf = 0, ncap = capcnt;
            float sfree = 0.0f;
            #pragma unroll
            for (int i = 0; i < NTAPS / 2; ++i) {
                const float w0x = clipu(a2[i].x - tau0);
                const float w0y = clipu(a2[i].y - tau0);
                const bool fx = (w0x > EPS) && (w0x < ucut);
                const bool fy = (w0y > EPS) && (w0y < ucut);
                nf += fx ? 1 : 0;          nf += fy ? 1 : 0;
                sfree += fx ? a2[i].x : 0.0f;
                sfree += fy ? a2[i].y : 0.0f;
                ncap += (w0x >= ucut) ? 1 : 0;
                ncap += (w0y >= ucut) ? 1 : 0;
            }
            nf_total = nf;
            tau = (sfree + MAX_W * (float)ncap - 1.0f) / fmaxf((float)nf, 1.0f);
        }
    }

    if (!fastpath) {
        // ---- Fallback: valid bracket (compute min/max lazily) ----
        if (!have_fb) {
            float mn = zp[0].x, mx = zp[0].x;
            #pragma unroll
            for (int k = 0; k < 32; ++k) {
                mn = fminf(mn, fminf(zp[k].x, zp[k].y));
                mx = fmaxf(mx, fmaxf(zp[k].x, zp[k].y));
            }
            fbLo = wave_min(mn) - 1.0f;
            fbHi = wave_max(mx);
        }
        float lo = fbLo, hi = fbHi;
        for (int it = 0; it < FB_ITERS; ++it) {
            const float mid = 0.5f * (lo + hi);
            const float s = wave_sum(scan_sum(zp, mid));
            const bool too_big = s > 1.0f;
            lo = too_big ? mid : lo;
            hi = too_big ? hi : mid;
        }
        tau0 = 0.5f * (lo + hi);
        // Full active-set pass.
        f32x2 nt0; nt0.x = -tau0; nt0.y = -tau0;
        float sf0 = 0.0f, sf1 = 0.0f;
        int nf_i = 0, nc_i = 0;
        #pragma unroll
        for (int k = 0; k < 32; k += 2) {
            f32x2 q0, q1;
            PKADD(q0, zp[k],   nt0);
            PKADD(q1, zp[k+1], nt0);
            const float wa = clipu(q0.x), wb = clipu(q0.y);
            const float wc = clipu(q1.x), wd = clipu(q1.y);
            const bool fa = (wa > EPS) && (wa < ucut);
            const bool fb = (wb > EPS) && (wb < ucut);
            const bool fc = (wc > EPS) && (wc < ucut);
            const bool fd = (wd > EPS) && (wd < ucut);
            sf0 += fa ? zp[k].x   : 0.0f;
            sf1 += fb ? zp[k].y   : 0.0f;
            sf0 += fc ? zp[k+1].x : 0.0f;
            sf1 += fd ? zp[k+1].y : 0.0f;
            nf_i += (fa ? 1 : 0) + (fb ? 1 : 0) + (fc ? 1 : 0) + (fd ? 1 : 0);
            nc_i += (wa >= ucut) + (wb >= ucut) + (wc >= ucut) + (wd >= ucut);
        }
        const float s_free = wave_sum(sf0 + sf1);
        nf_i = wave_isum(nf_i);
        nc_i = wave_isum(nc_i);
        nf_total = nf_i;
        tau = (s_free + MAX_W * (float)nc_i - 1.0f) / fmaxf((float)nf_i, 1.0f);
    }

    if (nf_total > 0) {
        // ---- Fast final write: med3(z - tau, 0, u), non-temporal ----
        f32x2 ntau; ntau.x = -tau; ntau.y = -tau;
        #pragma unroll
        for (int k = 0; k < 16; ++k) {
            f32x2 q0, q1;
            PKADD(q0, zp[2*k],   ntau);
            PKADD(q1, zp[2*k+1], ntau);
            f32x4 o;
            o.x = clipu(q0.x); o.y = clipu(q0.y);
            o.z = clipu(q1.x); o.w = clipu(q1.y);
            __builtin_nontemporal_store(o, &outr[k * 64 + lane]);
        }
    } else {
        // ---- n_free == 0: classification write (reference ignores its tau) ----
        const float capAt0 = tau0 + ucut;
        #pragma unroll
        for (int k = 0; k < 16; ++k) {
            f32x4 o;
            o.x = (zp[2*k].x   >= capAt0) ? MAX_W : 0.0f;
            o.y = (zp[2*k].y   >= capAt0) ? MAX_W : 0.0f;
            o.z = (zp[2*k+1].x >= capAt0) ? MAX_W : 0.0f;
            o.w = (zp[2*k+1].y >= capAt0) ? MAX_W : 0.0f;
            __builtin_nontemporal_store(o, &outr[k * 64 + lane]);
        }
    }
}

extern "C" void kernel_launch(void* const* d_in, const int* in_sizes, int n_in,
                              void* d_out, int out_size, void* d_ws, size_t ws_size,
                              hipStream_t stream) {
    const float* x    = (const float*)d_in[0];
    const float* temp = (const float*)d_in[1];
    float* out = (float*)d_out;
    (void)in_sizes; (void)n_in; (void)out_size; (void)d_ws; (void)ws_size;

    dim3 grid(N_SAMPLES / 4);   // 4 rows (waves) per 256-thread block
    dim3 block(256);
    hipLaunchKernelGGL(sparsemax_alloc_kernel, grid, block, 0, stream, x, temp, out);
}

// Round 16
// 78.630 us; speedup vs baseline: 1.0437x; 1.0437x over previous
//
#include <hip/hip_runtime.h>

// Capped simplex projection: per row, w = clip(z - tau, 0, u), sum(w) = 1.
// One wave (64 lanes) per row; 64 fp32 elements per lane in registers.
//
// R15 = R11 verbatim (best-measured config, 78.1us):
//  - Load loop fuses min/max/sum(z^2) as INDEPENDENT accumulators (does not
//    break the load pipeline, unlike R12's fused compaction).
//  - sigma-seeded probe band {2.10,2.40}*sigma-hat; band compaction to 6
//    LDS slots/lane; band-local count bisection (10 iters, counts from 6
//    regs + 1 DPP isum); 3x 64-way multisection rounds on <=24 taps;
//    tap-only epilogue; med3 NT-store write (n_free>0) or classification
//    write (n_free==0).
//  - Always-correct fallback (probe miss / slot overflow / tap overflow):
//    full sum-scan bisection + full epilogue.
// Memory-bound: 131MB fetch (L3 absorbs half of x) + 262MB NT write at
// ~80% of achievable mixed-stream BW.

#define N_ASSETS 4096
#define N_SAMPLES 16384
#define MAX_W 0.02f
#define EPS 1e-7f
#define KRANK 50             // ceil(1 / MAX_W)
#define FB_ITERS 17          // fallback sum-scan iterations
#define MS_ROUNDS 3          // multisection rounds (6 bits each)
#define NTAPS 24
#define BB_ITERS 10          // band-local bisect iterations
#define T1MULT 2.10f
#define T2MULT 2.40f

typedef __attribute__((ext_vector_type(2))) float f32x2;
typedef __attribute__((ext_vector_type(4))) float f32x4;

#define PKADD(d, a, b) asm("v_pk_add_f32 %0, %1, %2" : "=v"(d) : "v"(a), "v"(b))
#define PKMUL(d, a, b) asm("v_pk_mul_f32 %0, %1, %2" : "=v"(d) : "v"(a), "v"(b))
#define PKFMA(d, a, b, c) asm("v_pk_fma_f32 %0, %1, %2, %3" : "=v"(d) : "v"(a), "v"(b), "v"(c))

__device__ __forceinline__ float clipu(float v) {
    return __builtin_amdgcn_fmed3f(v, 0.0f, MAX_W);
}
__device__ __forceinline__ float bc_int_as_f(int v) {
    union { int i; float f; } u; u.i = v; return u.f;
}
__device__ __forceinline__ int bc_f_as_int(float v) {
    union { int i; float f; } u; u.f = v; return u.i;
}

template <int CTRL, int RMASK, bool BC>
__device__ __forceinline__ float dpp_add_step(float x) {
    int t = __builtin_amdgcn_update_dpp(0, bc_f_as_int(x), CTRL, RMASK, 0xF, BC);
    return x + bc_int_as_f(t);
}
__device__ __forceinline__ float wave_sum(float v) {
    v = dpp_add_step<0x111, 0xF, true>(v);
    v = dpp_add_step<0x112, 0xF, true>(v);
    v = dpp_add_step<0x114, 0xF, true>(v);
    v = dpp_add_step<0x118, 0xF, true>(v);
    v = dpp_add_step<0x142, 0xA, false>(v);
    v = dpp_add_step<0x143, 0xC, false>(v);
    return bc_int_as_f(__builtin_amdgcn_readlane(bc_f_as_int(v), 63));
}
template <int CTRL, int RMASK, bool BC>
__device__ __forceinline__ int dpp_iadd_step(int x) {
    int t = __builtin_amdgcn_update_dpp(0, x, CTRL, RMASK, 0xF, BC);
    return x + t;
}
__device__ __forceinline__ int wave_isum(int v) {
    v = dpp_iadd_step<0x111, 0xF, true>(v);
    v = dpp_iadd_step<0x112, 0xF, true>(v);
    v = dpp_iadd_step<0x114, 0xF, true>(v);
    v = dpp_iadd_step<0x118, 0xF, true>(v);
    v = dpp_iadd_step<0x142, 0xA, false>(v);
    v = dpp_iadd_step<0x143, 0xC, false>(v);
    return __builtin_amdgcn_readlane(v, 63);
}
template <int CTRL, int RMASK>
__device__ __forceinline__ float dpp_min_step(float x) {
    int xi = bc_f_as_int(x);
    int t = __builtin_amdgcn_update_dpp(xi, xi, CTRL, RMASK, 0xF, false);
    return fminf(x, bc_int_as_f(t));
}
template <int CTRL, int RMASK>
__device__ __forceinline__ float dpp_max_step(float x) {
    int xi = bc_f_as_int(x);
    int t = __builtin_amdgcn_update_dpp(xi, xi, CTRL, RMASK, 0xF, false);
    return fmaxf(x, bc_int_as_f(t));
}
__device__ __forceinline__ float wave_min(float v) {
    v = dpp_min_step<0x111, 0xF>(v); v = dpp_min_step<0x112, 0xF>(v);
    v = dpp_min_step<0x114, 0xF>(v); v = dpp_min_step<0x118, 0xF>(v);
    v = dpp_min_step<0x142, 0xA>(v); v = dpp_min_step<0x143, 0xC>(v);
    return bc_int_as_f(__builtin_amdgcn_readlane(bc_f_as_int(v), 63));
}
__device__ __forceinline__ float wave_max(float v) {
    v = dpp_max_step<0x111, 0xF>(v); v = dpp_max_step<0x112, 0xF>(v);
    v = dpp_max_step<0x114, 0xF>(v); v = dpp_max_step<0x118, 0xF>(v);
    v = dpp_max_step<0x142, 0xA>(v); v = dpp_max_step<0x143, 0xC>(v);
    return bc_int_as_f(__builtin_amdgcn_readlane(bc_f_as_int(v), 63));
}

// Full packed scan: sum of clip(z - mid) over 32 pairs (fallback path only).
__device__ __forceinline__ float scan_sum(const f32x2* zp, float mid) {
    f32x2 nm; nm.x = -mid; nm.y = -mid;
    f32x2 acc0 = {0.f, 0.f}, acc1 = {0.f, 0.f}, acc2 = {0.f, 0.f}, acc3 = {0.f, 0.f};
    #pragma unroll
    for (int k = 0; k < 32; k += 4) {
        f32x2 t0, t1, t2, t3;
        PKADD(t0, zp[k+0], nm);
        PKADD(t1, zp[k+1], nm);
        PKADD(t2, zp[k+2], nm);
        PKADD(t3, zp[k+3], nm);
        t0.x = clipu(t0.x); t0.y = clipu(t0.y);
        t1.x = clipu(t1.x); t1.y = clipu(t1.y);
        t2.x = clipu(t2.x); t2.y = clipu(t2.y);
        t3.x = clipu(t3.x); t3.y = clipu(t3.y);
        PKADD(acc0, acc0, t0);
        PKADD(acc1, acc1, t1);
        PKADD(acc2, acc2, t2);
        PKADD(acc3, acc3, t3);
    }
    PKADD(acc0, acc0, acc1);
    PKADD(acc2, acc2, acc3);
    PKADD(acc0, acc0, acc2);
    return acc0.x + acc0.y;
}

__global__ __launch_bounds__(256) void sparsemax_alloc_kernel(
    const float* __restrict__ x,
    const float* __restrict__ temperature,
    float* __restrict__ out) {

    __shared__ float band_lds[4][64][6];
    __shared__ float amb_lds[4][NTAPS];

    const int wave = threadIdx.x >> 6;          // 4 waves per block
    const int lane = threadIdx.x & 63;
    const int row  = blockIdx.x * 4 + wave;

    const float4* xr   = reinterpret_cast<const float4*>(x + (size_t)row * N_ASSETS);
    f32x4*        outr = reinterpret_cast<f32x4*>(out + (size_t)row * N_ASSETS);

    const float rt = 1.0f / temperature[row];
    f32x2 rt2; rt2.x = rt; rt2.y = rt;

    // ---- Load + fused stats (independent accumulators; pipeline-safe) ----
    f32x2 zp[32];
    float mn = 3.4e38f, mx = -3.4e38f;
    f32x2 ss0 = {0.f, 0.f}, ss1 = {0.f, 0.f};
    #pragma unroll
    for (int k = 0; k < 16; ++k) {
        float4 v = xr[k * 64 + lane];
        f32x2 lohalf, hihalf;
        lohalf.x = v.x; lohalf.y = v.y;
        hihalf.x = v.z; hihalf.y = v.w;
        PKMUL(zp[2*k],   lohalf, rt2);
        PKMUL(zp[2*k+1], hihalf, rt2);
        mn = fminf(mn, fminf(zp[2*k].x,   zp[2*k].y));
        mx = fmaxf(mx, fmaxf(zp[2*k].x,   zp[2*k].y));
        mn = fminf(mn, fminf(zp[2*k+1].x, zp[2*k+1].y));
        mx = fmaxf(mx, fmaxf(zp[2*k+1].x, zp[2*k+1].y));
        PKFMA(ss0, zp[2*k],   zp[2*k],   ss0);
        PKFMA(ss1, zp[2*k+1], zp[2*k+1], ss1);
    }
    mn = wave_min(mn);
    mx = wave_max(mx);
    PKADD(ss0, ss0, ss1);
    const float sig = sqrtf(wave_sum(ss0.x + ss0.y) * (1.0f / (float)N_ASSETS));

    const float t1 = T1MULT * sig;
    const float t2 = T2MULT * sig;
    const float bandLo = t1 - MAX_W;
    const float bandHi = t2 + MAX_W;

    // ---- Probe/compaction scan (separate pass over registers) ----
    float* slots = &band_lds[wave][lane][0];
    #pragma unroll
    for (int i = 0; i < 6; ++i) slots[i] = bandLo;   // sentinel

    int cBH = 0, bcnt = 0;
    #pragma unroll
    for (int k = 0; k < 32; ++k) {
        #pragma unroll
        for (int c = 0; c < 2; ++c) {
            const float zv = (c == 0) ? zp[k].x : zp[k].y;
            const bool hiB = zv > bandHi;
            cBH += hiB ? 1 : 0;
            const bool inB = (zv > bandLo) && !hiB;
            if (inB) {
                slots[bcnt < 6 ? bcnt : 5] = zv;
                ++bcnt;
            }
        }
    }
    asm volatile("s_waitcnt lgkmcnt(0)" ::: "memory");
    const float e0 = slots[0], e1 = slots[1], e2 = slots[2];
    const float e3 = slots[3], e4 = slots[4], e5 = slots[5];

    // Packed reduce: cBH (13b) | #{band>t1} (10b) | #{band>t2} (9b).
    int cg1 = (e0 > t1) + (e1 > t1) + (e2 > t1) + (e3 > t1) + (e4 > t1) + (e5 > t1);
    int cg2 = (e0 > t2) + (e1 > t2) + (e2 > t2) + (e3 > t2) + (e4 > t2) + (e5 > t2);
    const unsigned sred = (unsigned)wave_isum(cBH | (cg1 << 13) | (cg2 << 23));
    const int cBHt = (int)(sred & 0x1FFFu);
    const int c1   = cBHt + (int)((sred >> 13) & 0x3FFu);
    const int c2   = cBHt + (int)(sred >> 23);

    const bool ovf = __ballot(bcnt >= 7) != 0ULL;
    bool fastpath = (c1 >= KRANK) && (c2 < KRANK) && !ovf;

    float fbLo = 0.0f, fbHi = 0.0f;
    bool have_fb = false;
    float tau = 0.0f, tau0 = 0.0f;
    int nf_total = 0;
    const float ucut = MAX_W - EPS;

    if (fastpath) {
        // ---- Band-local count bisection (all counts from 6 regs) ----
        float clo = t1, chi = t2;
        int c_chi = c2;
        #pragma unroll
        for (int it = 0; it < BB_ITERS; ++it) {
            const float mid = 0.5f * (clo + chi);
            int pc = (e0 > mid) + (e1 > mid) + (e2 > mid)
                   + (e3 > mid) + (e4 > mid) + (e5 > mid);
            const int cc = cBHt + wave_isum(pc);
            const bool big = (cc >= KRANK);
            clo = big ? mid : clo;
            chi = big ? chi : mid;
            c_chi = big ? c_chi : cc;
        }
        const float Lo = clo - MAX_W;
        const float Hi = chi;
        const float capTh = Hi + MAX_W;

        // ---- Taps from band regs: elements in (Lo, capTh) ----
        float za = Lo, zb = Lo, zc = Lo;
        int tcnt = 0;
        {
            const float ee[6] = {e0, e1, e2, e3, e4, e5};
            #pragma unroll
            for (int i = 0; i < 6; ++i) {
                const bool tap = (ee[i] > Lo) && (ee[i] < capTh);
                za = (tap && tcnt == 0) ? ee[i] : za;
                zb = (tap && tcnt == 1) ? ee[i] : zb;
                zc = (tap && tcnt == 2) ? ee[i] : zc;
                tcnt += tap ? 1 : 0;
            }
        }
        const unsigned long long b1 = __ballot(tcnt >= 1);
        const unsigned long long b2 = __ballot(tcnt >= 2);
        const unsigned long long b3 = __ballot(tcnt >= 3);
        const unsigned long long b4 = __ballot(tcnt >= 4);
        int off = __builtin_amdgcn_mbcnt_hi((unsigned)(b1 >> 32),
                  __builtin_amdgcn_mbcnt_lo((unsigned)b1, 0));
        off    += __builtin_amdgcn_mbcnt_hi((unsigned)(b2 >> 32),
                  __builtin_amdgcn_mbcnt_lo((unsigned)b2, 0));
        off    += __builtin_amdgcn_mbcnt_hi((unsigned)(b3 >> 32),
                  __builtin_amdgcn_mbcnt_lo((unsigned)b3, 0));
        const int M = __popcll(b1) + __popcll(b2) + __popcll(b3);

        if (tcnt >= 1 && off     < NTAPS) amb_lds[wave][off]     = za;
        if (tcnt >= 2 && off + 1 < NTAPS) amb_lds[wave][off + 1] = zb;
        if (tcnt >= 3 && off + 2 < NTAPS) amb_lds[wave][off + 2] = zc;
        asm volatile("s_waitcnt lgkmcnt(0)" ::: "memory");

        if ((b4 != 0ULL) || (M > NTAPS)) {
            fastpath = false;            // rare: taps overflow -> tight FB bracket
            fbLo = Lo; fbHi = Hi; have_fb = true;
        } else {
            // capcnt = #{z >= capTh} = c_chi - #{band in (chi, capTh)}
            int pcc = ((e0 > chi) && (e0 < capTh)) + ((e1 > chi) && (e1 < capTh))
                    + ((e2 > chi) && (e2 < capTh)) + ((e3 > chi) && (e3 < capTh))
                    + ((e4 > chi) && (e4 < capTh)) + ((e5 > chi) && (e5 < capTh));
            const int capcnt = c_chi - wave_isum(pcc);
            const float capC = (float)capcnt * MAX_W;

            // ---- 64-way multisection over taps (closed form) ----
            f32x2 a2[NTAPS / 2];
            #pragma unroll
            for (int i = 0; i < NTAPS / 2; ++i) {
                a2[i].x = (2*i     < M) ? amb_lds[wave][2*i]     : Lo;
                a2[i].y = (2*i + 1 < M) ? amb_lds[wave][2*i + 1] : Lo;
            }
            float lo = Lo, hi = Hi;
            #pragma unroll
            for (int r = 0; r < MS_ROUNDS; ++r) {
                const float step = (hi - lo) * 0.015625f;
                const float tl = fmaf((float)(lane + 1), step, lo);
                f32x2 ntl; ntl.x = -tl; ntl.y = -tl;
                f32x2 acc0 = {0.f, 0.f}, acc1 = {0.f, 0.f};
                #pragma unroll
                for (int i = 0; i < NTAPS / 2; i += 2) {
                    f32x2 q0, q1;
                    PKADD(q0, a2[i],   ntl);
                    PKADD(q1, a2[i+1], ntl);
                    q0.x = clipu(q0.x); q0.y = clipu(q0.y);
                    q1.x = clipu(q1.x); q1.y = clipu(q1.y);
                    PKADD(acc0, acc0, q0);
                    PKADD(acc1, acc1, q1);
                }
                PKADD(acc0, acc0, acc1);
                const float s = capC + (acc0.x + acc0.y);
                const unsigned long long mask = __ballot(s > 1.0f);
                int j = __popcll(mask);
                j = (j > 63) ? 63 : j;
                const float lo_old = lo;
                lo = fmaf((float)j, step, lo_old);
                hi = fmaf((float)(j + 1), step, lo_old);
            }
            tau0 = 0.5f * (lo + hi);

            // ---- Epilogue over taps (wave-uniform) ----
            int nf = 0, ncap = capcnt;
            float sfree = 0.0f;
            #pragma unroll
            for (int i = 0; i < NTAPS / 2; ++i) {
                const float w0x = clipu(a2[i].x - tau0);
                const float w0y = clipu(a2[i].y - tau0);
                const bool fx = (w0x > EPS) && (w0x < ucut);
                const bool fy = (w0y > EPS) && (w0y < ucut);
                nf += fx ? 1 : 0;          nf += fy ? 1 : 0;
                sfree += fx ? a2[i].x : 0.0f;
                sfree += fy ? a2[i].y : 0.0f;
                ncap += (w0x >= ucut) ? 1 : 0;
                ncap += (w0y >= ucut) ? 1 : 0;
            }
            nf_total = nf;
            tau = (sfree + MAX_W * (float)ncap - 1.0f) / fmaxf((float)nf, 1.0f);
        }
    }

    if (!fastpath) {
        // ---- Fallback: valid bracket (compute from min/max if needed) ----
        if (!have_fb) {
            fbLo = mn - 1.0f;
            fbHi = mx;
        }
        float lo = fbLo, hi = fbHi;
        for (int it = 0; it < FB_ITERS; ++it) {
            const float mid = 0.5f * (lo + hi);
            const float s = wave_sum(scan_sum(zp, mid));
            const bool too_big = s > 1.0f;
            lo = too_big ? mid : lo;
            hi = too_big ? hi : mid;
        }
        tau0 = 0.5f * (lo + hi);
        // Full active-set pass.
        f32x2 nt0; nt0.x = -tau0; nt0.y = -tau0;
        float sf0 = 0.0f, sf1 = 0.0f;
        int nf_i = 0, nc_i = 0;
        #pragma unroll
        for (int k = 0; k < 32; k += 2) {
            f32x2 q0, q1;
            PKADD(q0, zp[k],   nt0);
            PKADD(q1, zp[k+1], nt0);
            const float wa = clipu(q0.x), wb = clipu(q0.y);
            const float wc = clipu(q1.x), wd = clipu(q1.y);
            const bool fa = (wa > EPS) && (wa < ucut);
            const bool fb = (wb > EPS) && (wb < ucut);
            const bool fc = (wc > EPS) && (wc < ucut);
            const bool fd = (wd > EPS) && (wd < ucut);
            sf0 += fa ? zp[k].x   : 0.0f;
            sf1 += fb ? zp[k].y   : 0.0f;
            sf0 += fc ? zp[k+1].x : 0.0f;
            sf1 += fd ? zp[k+1].y : 0.0f;
            nf_i += (fa ? 1 : 0) + (fb ? 1 : 0) + (fc ? 1 : 0) + (fd ? 1 : 0);
            nc_i += (wa >= ucut) + (wb >= ucut) + (wc >= ucut) + (wd >= ucut);
        }
        const float s_free = wave_sum(sf0 + sf1);
        nf_i = wave_isum(nf_i);
        nc_i = wave_isum(nc_i);
        nf_total = nf_i;
        tau = (s_free + MAX_W * (float)nc_i - 1.0f) / fmaxf((float)nf_i, 1.0f);
    }

    if (nf_total > 0) {
        // ---- Fast final write: med3(z - tau, 0, u), non-temporal ----
        f32x2 ntau; ntau.x = -tau; ntau.y = -tau;
        #pragma unroll
        for (int k = 0; k < 16; ++k) {
            f32x2 q0, q1;
            PKADD(q0, zp[2*k],   ntau);
            PKADD(q1, zp[2*k+1], ntau);
            f32x4 o;
            o.x = clipu(q0.x); o.y = clipu(q0.y);
            o.z = clipu(q1.x); o.w = clipu(q1.y);
            __builtin_nontemporal_store(o, &outr[k * 64 + lane]);
        }
    } else {
        // ---- n_free == 0: classification write (reference ignores its tau) ----
        const float capAt0 = tau0 + ucut;
        #pragma unroll
        for (int k = 0; k < 16; ++k) {
            f32x4 o;
            o.x = (zp[2*k].x   >= capAt0) ? MAX_W : 0.0f;
            o.y = (zp[2*k].y   >= capAt0) ? MAX_W : 0.0f;
            o.z = (zp[2*k+1].x >= capAt0) ? MAX_W : 0.0f;
            o.w = (zp[2*k+1].y >= capAt0) ? MAX_W : 0.0f;
            __builtin_nontemporal_store(o, &outr[k * 64 + lane]);
        }
    }
}

extern "C" void kernel_launch(void* const* d_in, const int* in_sizes, int n_in,
                              void* d_out, int out_size, void* d_ws, size_t ws_size,
                              hipStream_t stream) {
    const float* x    = (const float*)d_in[0];
    const float* temp = (const float*)d_in[1];
    float* out = (float*)d_out;
    (void)in_sizes; (void)n_in; (void)out_size; (void)d_ws; (void)ws_size;

    dim3 grid(N_SAMPLES / 4);   // 4 rows (waves) per 256-thread block
    dim3 block(256);
    hipLaunchKernelGGL(sparsemax_alloc_kernel, grid, block, 0, stream, x, temp, out);
}